// Round 5
// baseline (165.674 us; speedup 1.0000x reference)
//
#include <hip/hip_runtime.h>
#include <math.h>

typedef __bf16 bf16x8 __attribute__((ext_vector_type(8)));
typedef float f32x16 __attribute__((ext_vector_type(16)));

#define NTOK 131072
#define HDIM 128
#define ODIM 128
#define NEXP 8

__device__ __forceinline__ unsigned short f2bf(float f){
  union { float f; unsigned u; } v; v.f = f;
  unsigned r = v.u + 0x7FFFu + ((v.u >> 16) & 1u);
  return (unsigned short)(r >> 16);
}

// ---------------------------------------------------------------------------
// Kernel 1: pack W. Layout: [ot(4)][h(2)][e(8)][kt2(4)][l(64)][j(8)] bf16.
// A-frag (v_mfma_f32_32x32x16_bf16): A[m=l&31][k=(l>>5)*8+j]; o = ot*32+(l&31);
// k_global = (h*4+kt2)*16 + (l>>5)*8 + j. Bias NOT packed (epilogue handles it).
__global__ void pack_w(const float* __restrict__ we, unsigned short* __restrict__ pw){
  int f = blockIdx.x * 256 + threadIdx.x;       // 0..16383 (16B chunk id)
  int l   = f & 63;
  int kt2 = (f >> 6) & 3;
  int e   = (f >> 8) & 7;
  int h   = (f >> 11) & 1;
  int ot  = (f >> 12) & 3;
  int o = ot * 32 + (l & 31);
  int kbase = (h * 4 + kt2) * 16 + ((l >> 5) << 3);
  unsigned short vals[8];
#pragma unroll
  for (int j = 0; j < 8; ++j)
    vals[j] = f2bf(we[(e * HDIM + kbase + j) * ODIM + o]);
  *(bf16x8*)(pw + (size_t)f * 8) = *(bf16x8*)vals;
}

// ---------------------------------------------------------------------------
// Kernel 2: gating + x->bf16-frag pack. 64 tokens/block, 256 threads.
// All 4 waves compute quarter-row logit partials (LDS reduce), wave 0 finishes
// top-2+softmax -> gates_t[e][tok] (transposed, coalesced). All threads convert
// x to the global B-frag buffer xf[tgG][kt(8)][l(64)][j(8)] bf16 (32 MB).
__global__ void gating_pack(const float* __restrict__ x, const float* __restrict__ wg,
                            float* __restrict__ gates_t, unsigned short* __restrict__ xf){
  __shared__ float xs[64 * 128];   // [tok][f4-chunk c ^ (tok&7)] 32 KB
  __shared__ float wgl[128 * 8];   // 4 KB
  __shared__ float plg[64 * 36];   // [tok][q*8+e], stride 36 (pad) 9 KB
  int t = threadIdx.x;
  size_t tokbase = (size_t)blockIdx.x * 64;

  ((float4*)wgl)[t] = ((const float4*)wg)[t];
  {
    const float4* xsrc = (const float4*)(x + tokbase * HDIM);
#pragma unroll
    for (int i = 0; i < 8; ++i){
      int idx = i * 256 + t;
      int tok = idx >> 5, c = idx & 31;
      *(float4*)&xs[tok * 128 + ((c ^ (tok & 7)) << 2)] = xsrc[idx];
    }
  }
  __syncthreads();

  // quarter-row partial logits: token = t&63, quarter q = t>>6
  {
    int tok = t & 63, q = t >> 6;
    float lg[8];
#pragma unroll
    for (int e = 0; e < 8; ++e) lg[e] = 0.0f;
#pragma unroll
    for (int i = 0; i < 8; ++i){
      int c = q * 8 + i;
      float4 v = *(float4*)&xs[tok * 128 + ((c ^ (tok & 7)) << 2)];
      const float* wr = wgl + c * 32;
#pragma unroll
      for (int e = 0; e < 8; ++e)
        lg[e] += v.x * wr[e] + v.y * wr[8 + e] + v.z * wr[16 + e] + v.w * wr[24 + e];
    }
    *(float4*)&plg[tok * 36 + q * 8]     = make_float4(lg[0], lg[1], lg[2], lg[3]);
    *(float4*)&plg[tok * 36 + q * 8 + 4] = make_float4(lg[4], lg[5], lg[6], lg[7]);
  }
  __syncthreads();

  if (t < 64){
    float lg[8];
#pragma unroll
    for (int e = 0; e < 8; ++e)
      lg[e] = plg[t * 36 + e] + plg[t * 36 + 8 + e] + plg[t * 36 + 16 + e] + plg[t * 36 + 24 + e];
    // top-2, ties -> lowest index (matches lax.top_k)
    int i1 = 0; float v1 = lg[0];
#pragma unroll
    for (int e = 1; e < 8; ++e) if (lg[e] > v1){ v1 = lg[e]; i1 = e; }
    int i2 = -1; float v2 = -3.4e38f;
#pragma unroll
    for (int e = 0; e < 8; ++e) if (e != i1 && lg[e] > v2){ v2 = lg[e]; i2 = e; }
    float ex = __expf(v2 - v1);
    float inv = 1.0f / (1.0f + ex);
#pragma unroll
    for (int e = 0; e < 8; ++e)
      gates_t[(size_t)e * NTOK + tokbase + t] = (e == i1) ? inv : ((e == i2) ? ex * inv : 0.0f);
  }

  // convert to global B-frag buffer (reads xs only; no barrier needed)
  // B-frag: element j of chunk [tgG][kt][lslot] = x[tgG*32+(lslot&31)][kt*16+(lslot>>5)*8+j]
  {
    int tokL = t >> 2, q = t & 3;
    float4 cv[8];
#pragma unroll
    for (int i = 0; i < 8; ++i)
      cv[i] = *(float4*)&xs[tokL * 128 + (((q * 8 + i) ^ (tokL & 7)) << 2)];
    size_t tgG = (size_t)blockIdx.x * 2 + (tokL >> 5);
#pragma unroll
    for (int jb = 0; jb < 4; ++jb){
      int h0 = q * 32 + jb * 8;
      int kt = h0 >> 4;
      int lslot = (tokL & 31) + 32 * (jb & 1);
      float4 a = cv[2 * jb], b = cv[2 * jb + 1];
      unsigned long long lo = (unsigned long long)f2bf(a.x)
                            | ((unsigned long long)f2bf(a.y) << 16)
                            | ((unsigned long long)f2bf(a.z) << 32)
                            | ((unsigned long long)f2bf(a.w) << 48);
      unsigned long long hi = (unsigned long long)f2bf(b.x)
                            | ((unsigned long long)f2bf(b.y) << 16)
                            | ((unsigned long long)f2bf(b.z) << 32)
                            | ((unsigned long long)f2bf(b.w) << 48);
      unsigned long long* dst = (unsigned long long*)(xf + ((tgG * 8 + kt) * 64 + lslot) * 8);
      dst[0] = lo; dst[1] = hi;
    }
  }
}

// ---------------------------------------------------------------------------
// Kernel 3: pure MFMA GEMM. Block: 1 o-tile (32 o's) x 512 tokens, 256 thr.
// Wave w: 4 token-groups (tg = w*4..w*4+3), R_a=4 reuse of each W frag.
// W kt-half (32 KB) staged in LDS (re-staged for h=1); x-frags -> REGISTERS
// via perfectly coalesced 1-KB wave loads from xf. tot/xb fully unrolled,
// constant indices only (R1-R3 scratch lesson). LDS 50 KB -> 3 blocks/CU.
__launch_bounds__(256, 2)
__global__ void moe_gemm(const unsigned short* __restrict__ pw,
                         const unsigned short* __restrict__ xf,
                         const float* __restrict__ gates_t,
                         const float* __restrict__ be, float* __restrict__ out){
  __shared__ unsigned short Wh[16384];   // 32 KB: [e8][kt2(4)][l64][j8]
  __shared__ float glds[8 * 512];        // 16 KB: [e][tok512]
  __shared__ float blds[256];            //  1 KB: [e8][o32]

  int t = threadIdx.x;
  int ot = blockIdx.x & 3;
  int tb = blockIdx.x >> 2;
  int w = t >> 6, l = t & 63, l32 = l & 31, lh = l >> 5;
  size_t tokb = (size_t)tb * 512;

  // stage gates (coalesced) + bias slice
#pragma unroll
  for (int it = 0; it < 4; ++it){
    int idx = it * 256 + t;
    int e = idx >> 7, c = idx & 127;
    *(float4*)&glds[e * 512 + c * 4] =
      *(const float4*)&gates_t[(size_t)e * NTOK + tokb + c * 4];
  }
  blds[t] = be[(t >> 5) * ODIM + ot * 32 + (t & 31)];

  f32x16 zero16;
#pragma unroll
  for (int i = 0; i < 16; ++i) zero16[i] = 0.0f;
  f32x16 tot0 = zero16, tot1 = zero16, tot2 = zero16, tot3 = zero16;

#pragma unroll 1
  for (int h = 0; h < 2; ++h){
    // stage W-half (coalesced 16B chunks)
    {
      const uint4* wsrc = (const uint4*)(pw + (size_t)(ot * 2 + h) * 16384);
      uint4* wdst = (uint4*)Wh;
#pragma unroll
      for (int it = 0; it < 8; ++it)
        wdst[it * 256 + t] = wsrc[it * 256 + t];
    }
    // x B-frags -> regs (1 KB contiguous per wave-load)
    bf16x8 xb[4][4];
#pragma unroll
    for (int tg = 0; tg < 4; ++tg){
      size_t tgG = tokb / 32 + w * 4 + tg;
#pragma unroll
      for (int kt = 0; kt < 4; ++kt)
        xb[tg][kt] = *(const bf16x8*)(xf + ((tgG * 8 + h * 4 + kt) * 64 + l) * 8);
    }
    __syncthreads();   // Wh ready (and glds ready on h=0)

#pragma unroll 1
    for (int e = 0; e < 8; ++e){
      float g0 = glds[e * 512 + (w * 4 + 0) * 32 + l32];
      float g1 = glds[e * 512 + (w * 4 + 1) * 32 + l32];
      float g2 = glds[e * 512 + (w * 4 + 2) * 32 + l32];
      float g3 = glds[e * 512 + (w * 4 + 3) * 32 + l32];
      {
        f32x16 p0 = zero16, p1 = zero16;
#pragma unroll
        for (int kt = 0; kt < 4; ++kt){
          bf16x8 a = *(const bf16x8*)&Wh[((e * 4 + kt) * 64 + l) * 8];
          p0 = __builtin_amdgcn_mfma_f32_32x32x16_bf16(a, xb[0][kt], p0, 0, 0, 0);
          p1 = __builtin_amdgcn_mfma_f32_32x32x16_bf16(a, xb[1][kt], p1, 0, 0, 0);
        }
#pragma unroll
        for (int r = 0; r < 16; ++r){ tot0[r] += g0 * p0[r]; tot1[r] += g1 * p1[r]; }
      }
      {
        f32x16 p0 = zero16, p1 = zero16;
#pragma unroll
        for (int kt = 0; kt < 4; ++kt){
          bf16x8 a = *(const bf16x8*)&Wh[((e * 4 + kt) * 64 + l) * 8];
          p0 = __builtin_amdgcn_mfma_f32_32x32x16_bf16(a, xb[2][kt], p0, 0, 0, 0);
          p1 = __builtin_amdgcn_mfma_f32_32x32x16_bf16(a, xb[3][kt], p1, 0, 0, 0);
        }
#pragma unroll
        for (int r = 0; r < 16; ++r){ tot2[r] += g2 * p0[r]; tot3[r] += g3 * p1[r]; }
      }
    }
    __syncthreads();   // e-loop reads done before Wh re-stage / epilogue
  }

  // epilogue: bias (b_expert weighted by gates) + direct stores.
  // C/D map: token(col) = l32, o = ot*32 + rg*8 + lh*4 + rr  (r = rg*4+rr)
#pragma unroll
  for (int e = 0; e < 8; ++e){
    float bb[16];
#pragma unroll
    for (int rg = 0; rg < 4; ++rg){
      float4 b4 = *(float4*)&blds[e * 32 + rg * 8 + lh * 4];
      bb[rg * 4 + 0] = b4.x; bb[rg * 4 + 1] = b4.y; bb[rg * 4 + 2] = b4.z; bb[rg * 4 + 3] = b4.w;
    }
    float g0 = glds[e * 512 + (w * 4 + 0) * 32 + l32];
    float g1 = glds[e * 512 + (w * 4 + 1) * 32 + l32];
    float g2 = glds[e * 512 + (w * 4 + 2) * 32 + l32];
    float g3 = glds[e * 512 + (w * 4 + 3) * 32 + l32];
#pragma unroll
    for (int r = 0; r < 16; ++r){
      tot0[r] += g0 * bb[r]; tot1[r] += g1 * bb[r];
      tot2[r] += g2 * bb[r]; tot3[r] += g3 * bb[r];
    }
  }
#define STORE_TG(tg, tot)                                                       \
  {                                                                             \
    float* orow = out + (tokb + (size_t)(w * 4 + tg) * 32 + l32) * ODIM + ot * 32; \
    _Pragma("unroll")                                                           \
    for (int rg = 0; rg < 4; ++rg)                                              \
      *(float4*)(orow + rg * 8 + lh * 4) =                                      \
        make_float4(tot[rg * 4 + 0], tot[rg * 4 + 1], tot[rg * 4 + 2], tot[rg * 4 + 3]); \
  }
  STORE_TG(0, tot0) STORE_TG(1, tot1) STORE_TG(2, tot2) STORE_TG(3, tot3)
#undef STORE_TG
}

// ---------------------------------------------------------------------------
extern "C" void kernel_launch(void* const* d_in, const int* in_sizes, int n_in,
                              void* d_out, int out_size, void* d_ws, size_t ws_size,
                              hipStream_t stream){
  const float* x  = (const float*)d_in[0];
  const float* wg = (const float*)d_in[1];
  // d_in[2] = w_noise (inactive in eval mode)
  const float* we = (const float*)d_in[3];
  const float* be = (const float*)d_in[4];
  // d_in[5] = top_k (== 2, baked in)
  float* out = (float*)d_out;

  unsigned short* pw      = (unsigned short*)d_ws;                    // 256 KB
  float*          gates_t = (float*)((char*)d_ws + 262144);           // 4 MB
  unsigned short* xf      = (unsigned short*)((char*)d_ws + 4456448); // 32 MB

  pack_w     <<<64,   256, 0, stream>>>(we, pw);
  gating_pack<<<2048, 256, 0, stream>>>(x, wg, gates_t, xf);
  moe_gemm   <<<1024, 256, 0, stream>>>(pw, xf, gates_t, be, out);
}